// Round 1
// baseline (13672.520 us; speedup 1.0000x reference)
//
#include <hip/hip_runtime.h>
#include <cstdint>

typedef __attribute__((ext_vector_type(4))) float f32x4;
typedef __attribute__((ext_vector_type(8))) short s16x8;
typedef unsigned short u16;
typedef unsigned int u32;
typedef __attribute__((address_space(1))) void gas_void;
typedef __attribute__((address_space(3))) void las_void;

#define B_ 4
#define T_ 1024
#define V_ 32000
#define D_ 1024
#define H_ 16
#define HS_ 64
#define FF_ 4096
#define L_ 8
#define BT_ (B_ * T_)

__device__ __forceinline__ float bf2f(u16 h) { return __uint_as_float(((u32)h) << 16); }
__device__ __forceinline__ u16 f2bf(float f) {
  u32 u = __float_as_uint(f);
  u += 0x7fffu + ((u >> 16) & 1u);
  return (u16)(u >> 16);
}
__device__ __forceinline__ float bflo(u32 u) { return __uint_as_float(u << 16); }
__device__ __forceinline__ float bfhi(u32 u) { return __uint_as_float(u & 0xffff0000u); }

// async global->LDS, 16B per lane; lds dest must be wave-uniform base (+lane*16 by HW)
__device__ __forceinline__ void gld16(const void* g, void* l) {
  __builtin_amdgcn_global_load_lds((gas_void*)(uintptr_t)g,
                                   (las_void*)(u32)(uintptr_t)l, 16, 0, 0);
}

// ---------------------------------------------------------------------------
// GEMM: C[M,N] = A[M,K] @ B[K,N], A bf16 row-major, Bt = B^T bf16 [N][K].
// EPI: 0 = bf16 out plain; 1 = f32 out + bias + residual(in-place Cf);
//      2 = bf16 out + bias + relu; 3 = f32 out + bias.
// 128x128 tile, BK=32, 4 waves (2x2) of 64x64, mfma_f32_16x16x32_bf16.
// LDS linear dest via global_load_lds; 16B-chunk XOR swizzle (chunk ^= row&3)
// applied on the global source; ds_read_b128 fragment reads with same XOR.
// ---------------------------------------------------------------------------
template <int EPI>
__global__ __launch_bounds__(256) void gemm_bt(
    const u16* __restrict__ A, const u16* __restrict__ Bt,
    const float* __restrict__ bias, float* Cf, u16* Cb,
    int M, int N, int K) {
  __shared__ u16 lds[2][2][4096];  // [buf][A/B][128*32] = 32 KiB
  const int tid = threadIdx.x;
  const int lane = tid & 63;
  const int lr = lane & 15, hi = lane >> 4;
  const int wid = tid >> 6;
  const int wm = wid >> 1, wn = wid & 1;
  const int row0 = blockIdx.y << 7, col0 = blockIdx.x << 7;
  const int NT = K >> 5;
  const int wbase = (tid & ~63) << 4;  // wid*1024 bytes (wave-uniform)

  f32x4 acc[4][4];
#pragma unroll
  for (int i = 0; i < 4; ++i)
#pragma unroll
    for (int j = 0; j < 4; ++j) acc[i][j] = f32x4{0.f, 0.f, 0.f, 0.f};

  auto stage = [&](int buf, int kt) {
#pragma unroll
    for (int c = 0; c < 2; ++c) {
      const int o = (c << 12) + (tid << 4);   // dest byte in 8KB tile
      const int r = o >> 6;                   // row 0..127 (64B rows)
      const int il = (o & 63) ^ ((r & 3) << 4);  // logical in-row byte
      gld16(A + (size_t)(row0 + r) * K + (kt << 5) + (il >> 1),
            (char*)&lds[buf][0][0] + (c << 12) + wbase);
      gld16(Bt + (size_t)(col0 + r) * K + (kt << 5) + (il >> 1),
            (char*)&lds[buf][1][0] + (c << 12) + wbase);
    }
  };

  stage(0, 0);
  __syncthreads();
  int cur = 0;
  for (int kt = 0; kt < NT; ++kt) {
    if (kt + 1 < NT) stage(cur ^ 1, kt + 1);
    const char* As = (const char*)&lds[cur][0][0];
    const char* Bs = (const char*)&lds[cur][1][0];
    s16x8 af[4], bfr[4];
#pragma unroll
    for (int i = 0; i < 4; ++i) {
      const int ra = (wm << 6) + (i << 4) + lr;
      af[i] = *(const s16x8*)(As + (ra << 6) + (((hi ^ (ra & 3)) & 3) << 4));
      const int rb = (wn << 6) + (i << 4) + lr;
      bfr[i] = *(const s16x8*)(Bs + (rb << 6) + (((hi ^ (rb & 3)) & 3) << 4));
    }
#pragma unroll
    for (int i = 0; i < 4; ++i)
#pragma unroll
      for (int j = 0; j < 4; ++j)
        acc[i][j] =
            __builtin_amdgcn_mfma_f32_16x16x32_bf16(af[i], bfr[j], acc[i][j], 0, 0, 0);
    __syncthreads();
    cur ^= 1;
  }

  const int gr = row0 + (wm << 6);
  const int gc = col0 + (wn << 6);
#pragma unroll
  for (int j = 0; j < 4; ++j) {
    const int col = gc + (j << 4) + lr;
    const float bv = (EPI != 0) ? bias[col] : 0.f;
#pragma unroll
    for (int i = 0; i < 4; ++i) {
#pragma unroll
      for (int rg = 0; rg < 4; ++rg) {
        const int row = gr + (i << 4) + (hi << 2) + rg;
        const size_t off = (size_t)row * N + col;
        float val = acc[i][j][rg] + bv;
        if constexpr (EPI == 1) val += Cf[off];
        if constexpr (EPI == 2) val = fmaxf(val, 0.f);
        if constexpr (EPI == 0 || EPI == 2) Cb[off] = f2bf(val);
        else Cf[off] = val;
      }
    }
  }
}

// ---------------------------------------------------------------------------
// LayerNorm over D=1024, f32 in -> bf16 out. One block per row.
// ---------------------------------------------------------------------------
__global__ __launch_bounds__(256) void ln_kernel(const float* __restrict__ x,
                                                 const float* __restrict__ gw,
                                                 const float* __restrict__ bw,
                                                 u16* __restrict__ out) {
  const int r = blockIdx.x, tid = threadIdx.x;
  const int lane = tid & 63, wid = tid >> 6;
  __shared__ float red[8];
  f32x4 v = *(const f32x4*)(x + ((size_t)r << 10) + (tid << 2));
  float s = v[0] + v[1] + v[2] + v[3];
  float q = v[0] * v[0] + v[1] * v[1] + v[2] * v[2] + v[3] * v[3];
#pragma unroll
  for (int off = 32; off; off >>= 1) {
    s += __shfl_down(s, off);
    q += __shfl_down(q, off);
  }
  if (lane == 0) {
    red[wid] = s;
    red[4 + wid] = q;
  }
  __syncthreads();
  const float mean = (red[0] + red[1] + red[2] + red[3]) * (1.f / 1024.f);
  const float var = (red[4] + red[5] + red[6] + red[7]) * (1.f / 1024.f) - mean * mean;
  const float rstd = rsqrtf(var + 1e-5f);
  f32x4 g4 = *(const f32x4*)(gw + (tid << 2));
  f32x4 b4 = *(const f32x4*)(bw + (tid << 2));
  u16* op = out + ((size_t)r << 10) + (tid << 2);
#pragma unroll
  for (int j = 0; j < 4; ++j) op[j] = f2bf((v[j] - mean) * rstd * g4[j] + b4[j]);
}

// ---------------------------------------------------------------------------
// Embedding: x[r] = tok_emb[idx[r]] + pos_emb[r % T]
// ---------------------------------------------------------------------------
__global__ __launch_bounds__(256) void embed_kernel(const int* __restrict__ idx,
                                                    const float* __restrict__ tok,
                                                    const float* __restrict__ pos,
                                                    float* __restrict__ x) {
  const int r = blockIdx.x, tid = threadIdx.x;
  const int t = r & (T_ - 1);
  const int tk = idx[r];
  f32x4 a = *(const f32x4*)(tok + ((size_t)tk << 10) + (tid << 2));
  f32x4 p = *(const f32x4*)(pos + ((size_t)t << 10) + (tid << 2));
  *(f32x4*)(x + ((size_t)r << 10) + (tid << 2)) = a + p;
}

// ---------------------------------------------------------------------------
// Transpose + f32->bf16: src [K][N] f32 -> dst [N][K] bf16. 32x32 LDS tiles.
// ---------------------------------------------------------------------------
__global__ __launch_bounds__(256) void tconv_kernel(const float* __restrict__ src,
                                                    u16* __restrict__ dst, int K, int N) {
  __shared__ float tile[32][33];
  const int tx = threadIdx.x & 31, ty = threadIdx.x >> 5;
  const int n0 = blockIdx.x << 5, k0 = blockIdx.y << 5;
#pragma unroll
  for (int i = 0; i < 32; i += 8)
    tile[ty + i][tx] = src[(size_t)(k0 + ty + i) * N + n0 + tx];
  __syncthreads();
#pragma unroll
  for (int i = 0; i < 32; i += 8)
    dst[(size_t)(n0 + ty + i) * K + k0 + tx] = f2bf(tile[tx][ty + i]);
}

// ---------------------------------------------------------------------------
// Causal attention, one block (256 thr) per (b,h,t) row. qkv bf16 [B*T][3072]
// (cols: 0..1023 q, 1024..2047 k, 2048..3071 v; within each: h*64+hs).
// o bf16 [B*T][1024] (concat-head layout).
// ---------------------------------------------------------------------------
__global__ __launch_bounds__(256) void attn_kernel(const u16* __restrict__ qkv,
                                                   u16* __restrict__ o) {
  const int t = blockIdx.x, h = blockIdx.y, b = blockIdx.z;
  const int tid = threadIdx.x;
  const int lane = tid & 63, wid = tid >> 6;
  __shared__ float qs[64];
  __shared__ float sc[1024];
  __shared__ float red[8];
  __shared__ float osum[4][64];
  const size_t base = (size_t)(b * T_ + t) * 3072;
  if (tid < 64) qs[tid] = bf2f(qkv[base + (h << 6) + tid]);
  __syncthreads();
  float pmax = -1e30f;
  for (int s = tid; s <= t; s += 256) {
    const u16* kr = qkv + (size_t)(b * T_ + s) * 3072 + 1024 + (h << 6);
    const uint4* k4 = (const uint4*)kr;
    float a = 0.f;
#pragma unroll
    for (int dv = 0; dv < 8; ++dv) {
      uint4 pk = k4[dv];
      const float* qp = qs + (dv << 3);
      a += qp[0] * bflo(pk.x) + qp[1] * bfhi(pk.x) + qp[2] * bflo(pk.y) +
           qp[3] * bfhi(pk.y) + qp[4] * bflo(pk.z) + qp[5] * bfhi(pk.z) +
           qp[6] * bflo(pk.w) + qp[7] * bfhi(pk.w);
    }
    const float sv = a * 0.125f;
    sc[s] = sv;
    pmax = fmaxf(pmax, sv);
  }
#pragma unroll
  for (int off = 32; off; off >>= 1) pmax = fmaxf(pmax, __shfl_down(pmax, off));
  if (lane == 0) red[wid] = pmax;
  __syncthreads();
  const float mx = fmaxf(fmaxf(red[0], red[1]), fmaxf(red[2], red[3]));
  float psum = 0.f;
  for (int s = tid; s <= t; s += 256) {
    const float e = __expf(sc[s] - mx);
    sc[s] = e;
    psum += e;
  }
#pragma unroll
  for (int off = 32; off; off >>= 1) psum += __shfl_down(psum, off);
  if (lane == 0) red[4 + wid] = psum;
  __syncthreads();
  const float inv = 1.f / (red[4] + red[5] + red[6] + red[7]);
  const int d = tid & 63, sg = tid >> 6;
  float oa = 0.f;
  for (int s = sg; s <= t; s += 4)
    oa += sc[s] * bf2f(qkv[(size_t)(b * T_ + s) * 3072 + 2048 + (h << 6) + d]);
  osum[sg][d] = oa;
  __syncthreads();
  if (sg == 0) {
    const float rv = (osum[0][d] + osum[1][d] + osum[2][d] + osum[3][d]) * inv;
    o[(size_t)(b * T_ + t) * 1024 + (h << 6) + d] = f2bf(rv);
  }
}

// ---------------------------------------------------------------------------
extern "C" void kernel_launch(void* const* d_in, const int* in_sizes, int n_in,
                              void* d_out, int out_size, void* d_ws, size_t ws_size,
                              hipStream_t stream) {
  (void)in_sizes; (void)n_in; (void)out_size; (void)ws_size;
  const int* idx = (const int*)d_in[0];
  const float* tokE = (const float*)d_in[1];
  const float* posE = (const float*)d_in[2];
  const float* Wq = (const float*)d_in[3];
  const float* Wk = (const float*)d_in[4];
  const float* Wv = (const float*)d_in[5];
  const float* Wp = (const float*)d_in[6];
  const float* bp = (const float*)d_in[7];
  const float* ln1g = (const float*)d_in[8];
  const float* ln1b = (const float*)d_in[9];
  const float* ln2g = (const float*)d_in[10];
  const float* ln2b = (const float*)d_in[11];
  const float* W1 = (const float*)d_in[12];
  const float* b1 = (const float*)d_in[13];
  const float* W2 = (const float*)d_in[14];
  const float* b2 = (const float*)d_in[15];
  const float* lnfg = (const float*)d_in[16];
  const float* lnfb = (const float*)d_in[17];
  const float* Wlm = (const float*)d_in[18];
  const float* blm = (const float*)d_in[19];

  char* p = (char*)d_ws;
  float* x = (float*)p;   p += (size_t)BT_ * D_ * 4;
  u16* xn = (u16*)p;      p += (size_t)BT_ * D_ * 2;
  u16* qkv = (u16*)p;     p += (size_t)BT_ * 3072 * 2;
  u16* ob = (u16*)p;      p += (size_t)BT_ * D_ * 2;
  u16* hb = (u16*)p;      p += (size_t)BT_ * FF_ * 2;
  u16* WqkvT = (u16*)p;   p += (size_t)L_ * 3072 * D_ * 2;
  u16* WpT = (u16*)p;     p += (size_t)L_ * D_ * D_ * 2;
  u16* W1T = (u16*)p;     p += (size_t)L_ * FF_ * D_ * 2;
  u16* W2T = (u16*)p;     p += (size_t)L_ * D_ * FF_ * 2;
  u16* WlmT = (u16*)p;    p += (size_t)V_ * D_ * 2;

  dim3 blk(256);
  // weight convert+transpose (bf16, [N][K]) — every call (no caching allowed)
  for (int l = 0; l < L_; ++l) {
    tconv_kernel<<<dim3(32, 32), blk, 0, stream>>>(Wq + (size_t)l * D_ * D_,
                                                   WqkvT + (size_t)l * 3072 * D_, D_, D_);
    tconv_kernel<<<dim3(32, 32), blk, 0, stream>>>(
        Wk + (size_t)l * D_ * D_, WqkvT + (size_t)l * 3072 * D_ + D_ * D_, D_, D_);
    tconv_kernel<<<dim3(32, 32), blk, 0, stream>>>(
        Wv + (size_t)l * D_ * D_, WqkvT + (size_t)l * 3072 * D_ + 2 * D_ * D_, D_, D_);
    tconv_kernel<<<dim3(32, 32), blk, 0, stream>>>(Wp + (size_t)l * D_ * D_,
                                                   WpT + (size_t)l * D_ * D_, D_, D_);
    tconv_kernel<<<dim3(128, 32), blk, 0, stream>>>(W1 + (size_t)l * D_ * FF_,
                                                    W1T + (size_t)l * FF_ * D_, D_, FF_);
    tconv_kernel<<<dim3(32, 128), blk, 0, stream>>>(W2 + (size_t)l * FF_ * D_,
                                                    W2T + (size_t)l * D_ * FF_, FF_, D_);
  }
  tconv_kernel<<<dim3(1000, 32), blk, 0, stream>>>(Wlm, WlmT, D_, V_);

  embed_kernel<<<dim3(BT_), blk, 0, stream>>>(idx, tokE, posE, x);

  for (int l = 0; l < L_; ++l) {
    ln_kernel<<<dim3(BT_), blk, 0, stream>>>(x, ln1g + l * D_, ln1b + l * D_, xn);
    gemm_bt<0><<<dim3(24, 32), blk, 0, stream>>>(xn, WqkvT + (size_t)l * 3072 * D_,
                                                 nullptr, nullptr, qkv, BT_, 3072, D_);
    attn_kernel<<<dim3(T_, H_, B_), blk, 0, stream>>>(qkv, ob);
    gemm_bt<1><<<dim3(8, 32), blk, 0, stream>>>(ob, WpT + (size_t)l * D_ * D_,
                                                bp + l * D_, x, nullptr, BT_, D_, D_);
    ln_kernel<<<dim3(BT_), blk, 0, stream>>>(x, ln2g + l * D_, ln2b + l * D_, xn);
    gemm_bt<2><<<dim3(32, 32), blk, 0, stream>>>(xn, W1T + (size_t)l * FF_ * D_,
                                                 b1 + l * FF_, nullptr, hb, BT_, FF_, D_);
    gemm_bt<1><<<dim3(8, 32), blk, 0, stream>>>(hb, W2T + (size_t)l * D_ * FF_,
                                                b2 + l * D_, x, nullptr, BT_, D_, FF_);
  }
  ln_kernel<<<dim3(BT_), blk, 0, stream>>>(x, lnfg, lnfb, xn);
  gemm_bt<3><<<dim3(250, 32), blk, 0, stream>>>(xn, WlmT, blm, (float*)d_out, nullptr,
                                                BT_, V_, D_);
}

// Round 2
// 3130.675 us; speedup vs baseline: 4.3673x; 4.3673x over previous
//
#include <hip/hip_runtime.h>
#include <cstdint>

typedef __attribute__((ext_vector_type(4))) float f32x4;
typedef __attribute__((ext_vector_type(8))) short s16x8;
typedef unsigned short u16;
typedef unsigned int u32;
typedef __attribute__((address_space(1))) void gas_void;
typedef __attribute__((address_space(3))) void las_void;

#define B_ 4
#define T_ 1024
#define V_ 32000
#define D_ 1024
#define H_ 16
#define HS_ 64
#define FF_ 4096
#define L_ 8
#define BT_ (B_ * T_)

__device__ __forceinline__ float bf2f(u16 h) { return __uint_as_float(((u32)h) << 16); }
__device__ __forceinline__ u16 f2bf(float f) {
  u32 u = __float_as_uint(f);
  u += 0x7fffu + ((u >> 16) & 1u);
  return (u16)(u >> 16);
}

// async global->LDS, 16B per lane; lds dest must be wave-uniform base (+lane*16 by HW)
__device__ __forceinline__ void gld16(const void* g, void* l) {
  __builtin_amdgcn_global_load_lds((gas_void*)(uintptr_t)g,
                                   (las_void*)(u32)(uintptr_t)l, 16, 0, 0);
}

// ---------------------------------------------------------------------------
// GEMM: C[M,N] = A[M,K] @ B[K,N], A bf16 row-major, Bt = B^T bf16 [N][K].
// EPI: 0 = bf16 out plain; 1 = f32 out + bias + residual(in-place Cf);
//      2 = bf16 out + bias + relu; 3 = f32 out + bias.
// ---------------------------------------------------------------------------
template <int EPI>
__global__ __launch_bounds__(256) void gemm_bt(
    const u16* __restrict__ A, const u16* __restrict__ Bt,
    const float* __restrict__ bias, float* Cf, u16* Cb,
    int M, int N, int K) {
  __shared__ u16 lds[2][2][4096];  // [buf][A/B][128*32] = 32 KiB
  const int tid = threadIdx.x;
  const int lane = tid & 63;
  const int lr = lane & 15, hi = lane >> 4;
  const int wid = tid >> 6;
  const int wm = wid >> 1, wn = wid & 1;
  const int row0 = blockIdx.y << 7, col0 = blockIdx.x << 7;
  const int NT = K >> 5;
  const int wbase = (tid & ~63) << 4;  // wid*1024 bytes (wave-uniform)

  f32x4 acc[4][4];
#pragma unroll
  for (int i = 0; i < 4; ++i)
#pragma unroll
    for (int j = 0; j < 4; ++j) acc[i][j] = f32x4{0.f, 0.f, 0.f, 0.f};

  auto stage = [&](int buf, int kt) {
#pragma unroll
    for (int c = 0; c < 2; ++c) {
      const int o = (c << 12) + (tid << 4);   // dest byte in 8KB tile
      const int r = o >> 6;                   // row 0..127 (64B rows)
      const int il = (o & 63) ^ ((r & 3) << 4);  // logical in-row byte
      gld16(A + (size_t)(row0 + r) * K + (kt << 5) + (il >> 1),
            (char*)&lds[buf][0][0] + (c << 12) + wbase);
      gld16(Bt + (size_t)(col0 + r) * K + (kt << 5) + (il >> 1),
            (char*)&lds[buf][1][0] + (c << 12) + wbase);
    }
  };

  stage(0, 0);
  __syncthreads();
  int cur = 0;
  for (int kt = 0; kt < NT; ++kt) {
    if (kt + 1 < NT) stage(cur ^ 1, kt + 1);
    const char* As = (const char*)&lds[cur][0][0];
    const char* Bs = (const char*)&lds[cur][1][0];
    s16x8 af[4], bfr[4];
#pragma unroll
    for (int i = 0; i < 4; ++i) {
      const int ra = (wm << 6) + (i << 4) + lr;
      af[i] = *(const s16x8*)(As + (ra << 6) + (((hi ^ (ra & 3)) & 3) << 4));
      const int rb = (wn << 6) + (i << 4) + lr;
      bfr[i] = *(const s16x8*)(Bs + (rb << 6) + (((hi ^ (rb & 3)) & 3) << 4));
    }
#pragma unroll
    for (int i = 0; i < 4; ++i)
#pragma unroll
      for (int j = 0; j < 4; ++j)
        acc[i][j] =
            __builtin_amdgcn_mfma_f32_16x16x32_bf16(af[i], bfr[j], acc[i][j], 0, 0, 0);
    __syncthreads();
    cur ^= 1;
  }

  const int gr = row0 + (wm << 6);
  const int gc = col0 + (wn << 6);
#pragma unroll
  for (int j = 0; j < 4; ++j) {
    const int col = gc + (j << 4) + lr;
    const float bv = (EPI != 0) ? bias[col] : 0.f;
#pragma unroll
    for (int i = 0; i < 4; ++i) {
#pragma unroll
      for (int rg = 0; rg < 4; ++rg) {
        const int row = gr + (i << 4) + (hi << 2) + rg;
        const size_t off = (size_t)row * N + col;
        float val = acc[i][j][rg] + bv;
        if constexpr (EPI == 1) val += Cf[off];
        if constexpr (EPI == 2) val = fmaxf(val, 0.f);
        if constexpr (EPI == 0 || EPI == 2) Cb[off] = f2bf(val);
        else Cf[off] = val;
      }
    }
  }
}

// ---------------------------------------------------------------------------
// LayerNorm over D=1024, f32 in -> bf16 out. One block per row.
// ---------------------------------------------------------------------------
__global__ __launch_bounds__(256) void ln_kernel(const float* __restrict__ x,
                                                 const float* __restrict__ gw,
                                                 const float* __restrict__ bw,
                                                 u16* __restrict__ out) {
  const int r = blockIdx.x, tid = threadIdx.x;
  const int lane = tid & 63, wid = tid >> 6;
  __shared__ float red[8];
  f32x4 v = *(const f32x4*)(x + ((size_t)r << 10) + (tid << 2));
  float s = v[0] + v[1] + v[2] + v[3];
  float q = v[0] * v[0] + v[1] * v[1] + v[2] * v[2] + v[3] * v[3];
#pragma unroll
  for (int off = 32; off; off >>= 1) {
    s += __shfl_down(s, off);
    q += __shfl_down(q, off);
  }
  if (lane == 0) {
    red[wid] = s;
    red[4 + wid] = q;
  }
  __syncthreads();
  const float mean = (red[0] + red[1] + red[2] + red[3]) * (1.f / 1024.f);
  const float var = (red[4] + red[5] + red[6] + red[7]) * (1.f / 1024.f) - mean * mean;
  const float rstd = rsqrtf(var + 1e-5f);
  f32x4 g4 = *(const f32x4*)(gw + (tid << 2));
  f32x4 b4 = *(const f32x4*)(bw + (tid << 2));
  u16* op = out + ((size_t)r << 10) + (tid << 2);
#pragma unroll
  for (int j = 0; j < 4; ++j) op[j] = f2bf((v[j] - mean) * rstd * g4[j] + b4[j]);
}

// ---------------------------------------------------------------------------
// Embedding: x[r] = tok_emb[idx[r]] + pos_emb[r % T]
// ---------------------------------------------------------------------------
__global__ __launch_bounds__(256) void embed_kernel(const int* __restrict__ idx,
                                                    const float* __restrict__ tok,
                                                    const float* __restrict__ pos,
                                                    float* __restrict__ x) {
  const int r = blockIdx.x, tid = threadIdx.x;
  const int t = r & (T_ - 1);
  const int tk = idx[r];
  f32x4 a = *(const f32x4*)(tok + ((size_t)tk << 10) + (tid << 2));
  f32x4 p = *(const f32x4*)(pos + ((size_t)t << 10) + (tid << 2));
  *(f32x4*)(x + ((size_t)r << 10) + (tid << 2)) = a + p;
}

// ---------------------------------------------------------------------------
// Transpose + f32->bf16: src [K][N] f32 -> dst [N][K] bf16. 32x32 LDS tiles.
// ---------------------------------------------------------------------------
__global__ __launch_bounds__(256) void tconv_kernel(const float* __restrict__ src,
                                                    u16* __restrict__ dst, int K, int N) {
  __shared__ float tile[32][33];
  const int tx = threadIdx.x & 31, ty = threadIdx.x >> 5;
  const int n0 = blockIdx.x << 5, k0 = blockIdx.y << 5;
#pragma unroll
  for (int i = 0; i < 32; i += 8)
    tile[ty + i][tx] = src[(size_t)(k0 + ty + i) * N + n0 + tx];
  __syncthreads();
#pragma unroll
  for (int i = 0; i < 32; i += 8)
    dst[(size_t)(n0 + ty + i) * K + k0 + tx] = f2bf(tile[tx][ty + i]);
}

// ---------------------------------------------------------------------------
// Flash attention (causal). qkv bf16 [B*T][3072] (q|k|v, each h*64+hs).
// Block = 4 waves, one 64-row q-tile of one (b,h). Each wave: 16 q-rows.
// KV tiles of 64. MFMA 16x16x32 bf16 for QK^T and PV; online softmax in f32.
// K staged via global_load_lds (chunk-XOR swizzle on global source);
// V staged transposed (lane=kv scatter, conflict-free); P via per-wave LDS.
// ---------------------------------------------------------------------------
__global__ __launch_bounds__(256) void fattn_kernel(const u16* __restrict__ qkv,
                                                    u16* __restrict__ o) {
  const int qt = blockIdx.x, h = blockIdx.y, b = blockIdx.z;
  const int tid = threadIdx.x;
  const int lane = tid & 63;
  const int lr = lane & 15, hi = lane >> 4;
  const int w = tid >> 6;
  __shared__ u16 Kl[4096];      // [kv][64 d], 128B rows, chunk-swizzled
  __shared__ u16 Vt[4096];      // [d][64 kv], 128B rows, chunk-swizzled
  __shared__ u16 Pl[4][1024];   // per-wave P [16 q][64 kv], chunk-swizzled

  // Q fragments in registers: lane holds Q[q0+lr][kk*32+hi*8 ..+7]
  const int q_row = (qt << 6) + (w << 4) + lr;
  const size_t qbase = ((size_t)(b * T_) + q_row) * 3072 + (h << 6);
  s16x8 aq[2];
  aq[0] = *(const s16x8*)(qkv + qbase + hi * 8);
  aq[1] = *(const s16x8*)(qkv + qbase + 32 + hi * 8);

  f32x4 ofr[4];
  float m[4], lsum[4];
#pragma unroll
  for (int j = 0; j < 4; ++j) ofr[j] = f32x4{0.f, 0.f, 0.f, 0.f};
#pragma unroll
  for (int rg = 0; rg < 4; ++rg) { m[rg] = -1e30f; lsum[rg] = 0.f; }

  const size_t bT = (size_t)(b * T_);

  for (int kt = 0; kt <= qt; ++kt) {
    const int kv0 = kt << 6;
    // --- stage K via global_load_lds (2 shots x 4KB) ---
#pragma unroll
    for (int sh = 0; sh < 2; ++sh) {
      const int ob = (sh << 12) + (tid << 4);       // dest byte
      const int r = ob >> 7;                        // kv row 0..63
      const int il = (ob & 127) ^ ((r & 7) << 4);   // logical in-row byte
      gld16(qkv + (bT + kv0 + r) * 3072 + 1024 + (h << 6) + (il >> 1),
            (char*)Kl + (sh << 12) + ((tid & 192) << 4));
    }
    // --- stage V transposed: lane = kv row, wave covers 16 d per shot ---
#pragma unroll
    for (int sh = 0; sh < 2; ++sh) {
      const int c = (w << 1) + sh;                  // 16B chunk (8 d values)
      uint4 pv = *(const uint4*)(qkv + (bT + kv0 + lane) * 3072 + 2048 +
                                 (h << 6) + (c << 3));
#pragma unroll
      for (int j = 0; j < 8; ++j) {
        const int d = (c << 3) + j;
        Vt[(d << 6) + (lane ^ ((d & 7) << 3))] = ((const u16*)&pv)[j];
      }
    }
    __syncthreads();

    // --- S = Q K^T (8 MFMA) ---
    f32x4 s[4];
#pragma unroll
    for (int j = 0; j < 4; ++j) s[j] = f32x4{0.f, 0.f, 0.f, 0.f};
#pragma unroll
    for (int kk = 0; kk < 2; ++kk)
#pragma unroll
      for (int j = 0; j < 4; ++j) {
        const int rb = (j << 4) + lr;
        const s16x8 bk = *(const s16x8*)((const char*)Kl + (rb << 7) +
                                         ((((kk << 2) + hi) ^ (rb & 7)) << 4));
        s[j] = __builtin_amdgcn_mfma_f32_16x16x32_bf16(aq[kk], bk, s[j], 0, 0, 0);
      }

    // --- scale + causal mask (diagonal tile only) ---
    const bool diag = (kt == qt);
#pragma unroll
    for (int j = 0; j < 4; ++j) {
      f32x4 sv = s[j] * 0.125f;
      if (diag) {
        const int col = (j << 4) + lr;  // relative kv
#pragma unroll
        for (int rg = 0; rg < 4; ++rg) {
          const int row = (w << 4) + (hi << 2) + rg;  // relative q
          if (col > row) sv[rg] = -1e30f;
        }
      }
      s[j] = sv;
    }

    // --- online softmax (per-lane rows hi*4+rg; reduce across lr group) ---
#pragma unroll
    for (int rg = 0; rg < 4; ++rg) {
      float mx = fmaxf(fmaxf(s[0][rg], s[1][rg]), fmaxf(s[2][rg], s[3][rg]));
      mx = fmaxf(mx, __shfl_xor(mx, 1));
      mx = fmaxf(mx, __shfl_xor(mx, 2));
      mx = fmaxf(mx, __shfl_xor(mx, 4));
      mx = fmaxf(mx, __shfl_xor(mx, 8));
      const float mn = fmaxf(m[rg], mx);
      const float sc = __expf(m[rg] - mn);
      m[rg] = mn;
      float rs = 0.f;
#pragma unroll
      for (int j = 0; j < 4; ++j) {
        const float e = __expf(s[j][rg] - mn);
        s[j][rg] = e;
        rs += e;
      }
      rs += __shfl_xor(rs, 1);
      rs += __shfl_xor(rs, 2);
      rs += __shfl_xor(rs, 4);
      rs += __shfl_xor(rs, 8);
      lsum[rg] = lsum[rg] * sc + rs;
#pragma unroll
      for (int j2 = 0; j2 < 4; ++j2) ofr[j2][rg] *= sc;
    }

    // --- P -> per-wave LDS (bf16, chunk-swizzled) ---
#pragma unroll
    for (int j = 0; j < 4; ++j)
#pragma unroll
      for (int rg = 0; rg < 4; ++rg) {
        const int row = (hi << 2) + rg, col = (j << 4) + lr;
        Pl[w][(row << 6) + (col ^ ((row & 7) << 3))] = f2bf(s[j][rg]);
      }

    // --- O += P V (8 MFMA) ---
#pragma unroll
    for (int kk = 0; kk < 2; ++kk) {
      const s16x8 ap = *(const s16x8*)((const char*)&Pl[w][0] + (lr << 7) +
                                       (((kk << 6) + (hi << 4)) ^ ((lr & 7) << 4)));
#pragma unroll
      for (int j2 = 0; j2 < 4; ++j2) {
        const int rb = (j2 << 4) + lr;
        const s16x8 bv = *(const s16x8*)((const char*)Vt + (rb << 7) +
                                         ((((kk << 2) + hi) ^ (rb & 7)) << 4));
        ofr[j2] = __builtin_amdgcn_mfma_f32_16x16x32_bf16(ap, bv, ofr[j2], 0, 0, 0);
      }
    }
    __syncthreads();
  }

  // --- epilogue: normalize and store ---
  float rinv[4];
#pragma unroll
  for (int rg = 0; rg < 4; ++rg) rinv[rg] = 1.f / lsum[rg];
#pragma unroll
  for (int j2 = 0; j2 < 4; ++j2)
#pragma unroll
    for (int rg = 0; rg < 4; ++rg) {
      const int row = (qt << 6) + (w << 4) + (hi << 2) + rg;
      const int col = (h << 6) + (j2 << 4) + lr;
      o[(bT + row) * 1024 + col] = f2bf(ofr[j2][rg] * rinv[rg]);
    }
}

// ---------------------------------------------------------------------------
extern "C" void kernel_launch(void* const* d_in, const int* in_sizes, int n_in,
                              void* d_out, int out_size, void* d_ws, size_t ws_size,
                              hipStream_t stream) {
  (void)in_sizes; (void)n_in; (void)out_size; (void)ws_size;
  const int* idx = (const int*)d_in[0];
  const float* tokE = (const float*)d_in[1];
  const float* posE = (const float*)d_in[2];
  const float* Wq = (const float*)d_in[3];
  const float* Wk = (const float*)d_in[4];
  const float* Wv = (const float*)d_in[5];
  const float* Wp = (const float*)d_in[6];
  const float* bp = (const float*)d_in[7];
  const float* ln1g = (const float*)d_in[8];
  const float* ln1b = (const float*)d_in[9];
  const float* ln2g = (const float*)d_in[10];
  const float* ln2b = (const float*)d_in[11];
  const float* W1 = (const float*)d_in[12];
  const float* b1 = (const float*)d_in[13];
  const float* W2 = (const float*)d_in[14];
  const float* b2 = (const float*)d_in[15];
  const float* lnfg = (const float*)d_in[16];
  const float* lnfb = (const float*)d_in[17];
  const float* Wlm = (const float*)d_in[18];
  const float* blm = (const float*)d_in[19];

  char* p = (char*)d_ws;
  float* x = (float*)p;   p += (size_t)BT_ * D_ * 4;
  u16* xn = (u16*)p;      p += (size_t)BT_ * D_ * 2;
  u16* qkv = (u16*)p;     p += (size_t)BT_ * 3072 * 2;
  u16* ob = (u16*)p;      p += (size_t)BT_ * D_ * 2;
  u16* hb = (u16*)p;      p += (size_t)BT_ * FF_ * 2;
  u16* WqkvT = (u16*)p;   p += (size_t)L_ * 3072 * D_ * 2;
  u16* WpT = (u16*)p;     p += (size_t)L_ * D_ * D_ * 2;
  u16* W1T = (u16*)p;     p += (size_t)L_ * FF_ * D_ * 2;
  u16* W2T = (u16*)p;     p += (size_t)L_ * D_ * FF_ * 2;
  u16* WlmT = (u16*)p;    p += (size_t)V_ * D_ * 2;

  dim3 blk(256);
  // weight convert+transpose (bf16, [N][K]) — every call (no caching allowed)
  for (int l = 0; l < L_; ++l) {
    tconv_kernel<<<dim3(32, 32), blk, 0, stream>>>(Wq + (size_t)l * D_ * D_,
                                                   WqkvT + (size_t)l * 3072 * D_, D_, D_);
    tconv_kernel<<<dim3(32, 32), blk, 0, stream>>>(
        Wk + (size_t)l * D_ * D_, WqkvT + (size_t)l * 3072 * D_ + D_ * D_, D_, D_);
    tconv_kernel<<<dim3(32, 32), blk, 0, stream>>>(
        Wv + (size_t)l * D_ * D_, WqkvT + (size_t)l * 3072 * D_ + 2 * D_ * D_, D_, D_);
    tconv_kernel<<<dim3(32, 32), blk, 0, stream>>>(Wp + (size_t)l * D_ * D_,
                                                   WpT + (size_t)l * D_ * D_, D_, D_);
    tconv_kernel<<<dim3(128, 32), blk, 0, stream>>>(W1 + (size_t)l * D_ * FF_,
                                                    W1T + (size_t)l * FF_ * D_, D_, FF_);
    tconv_kernel<<<dim3(32, 128), blk, 0, stream>>>(W2 + (size_t)l * FF_ * D_,
                                                    W2T + (size_t)l * D_ * FF_, FF_, D_);
  }
  tconv_kernel<<<dim3(1000, 32), blk, 0, stream>>>(Wlm, WlmT, D_, V_);

  embed_kernel<<<dim3(BT_), blk, 0, stream>>>(idx, tokE, posE, x);

  for (int l = 0; l < L_; ++l) {
    ln_kernel<<<dim3(BT_), blk, 0, stream>>>(x, ln1g + l * D_, ln1b + l * D_, xn);
    gemm_bt<0><<<dim3(24, 32), blk, 0, stream>>>(xn, WqkvT + (size_t)l * 3072 * D_,
                                                 nullptr, nullptr, qkv, BT_, 3072, D_);
    fattn_kernel<<<dim3(T_ / 64, H_, B_), blk, 0, stream>>>(qkv, ob);
    gemm_bt<1><<<dim3(8, 32), blk, 0, stream>>>(ob, WpT + (size_t)l * D_ * D_,
                                                bp + l * D_, x, nullptr, BT_, D_, D_);
    ln_kernel<<<dim3(BT_), blk, 0, stream>>>(x, ln2g + l * D_, ln2b + l * D_, xn);
    gemm_bt<2><<<dim3(32, 32), blk, 0, stream>>>(xn, W1T + (size_t)l * FF_ * D_,
                                                 b1 + l * FF_, nullptr, hb, BT_, FF_, D_);
    gemm_bt<1><<<dim3(8, 32), blk, 0, stream>>>(hb, W2T + (size_t)l * D_ * FF_,
                                                b2 + l * D_, x, nullptr, BT_, D_, FF_);
  }
  ln_kernel<<<dim3(BT_), blk, 0, stream>>>(x, lnfg, lnfb, xn);
  gemm_bt<3><<<dim3(250, 32), blk, 0, stream>>>(xn, WlmT, blm, (float*)d_out, nullptr,
                                                BT_, V_, D_);
}